// Round 1
// baseline (6595.522 us; speedup 1.0000x reference)
//
#include <hip/hip_runtime.h>
#include <hip/hip_bf16.h>
#include <math.h>

typedef __attribute__((ext_vector_type(4))) float f32x4;
typedef __attribute__((ext_vector_type(8))) short s16x8;

#define BB 2
#define SS 1024
#define MEM 1024
#define DD 1024
#define LL 4
#define VV 32000
#define TT 2048
#define NH 16
#define DH 64

__device__ __forceinline__ short f2bf(float f) {
    unsigned u = __float_as_uint(f);
    u += 0x7fffu + ((u >> 16) & 1u);   // round-to-nearest-even
    return (short)(u >> 16);
}

__device__ __forceinline__ float gelu_f(float x) {
    return 0.5f * x * (1.0f + erff(x * 0.70710678118654752f));
}

// ---------------- GEMM: C(M,N) = act(A(M,K) @ W(K,N) + bias) ----------------
// A, W, C are f32 in global memory; staged into LDS as bf16, MFMA 16x16x32.
// Tile: BM=128, BN=64, BK=32. 4 waves, each owns a 64x32 sub-tile (4x2 frags).
#define GBM 128
#define GBN 64
#define GBK 32
#define GLD 40   // LDS row stride in shorts (32 + 8 pad -> 2-way-free frag reads)

__global__ __launch_bounds__(256) void gemm_kernel(
    const float* __restrict__ A, const float* __restrict__ W,
    const float* __restrict__ bias, float* __restrict__ C,
    int N, int K, int act)
{
    __shared__ short a_s[GBM][GLD];
    __shared__ short b_s[GBN][GLD];
    const int tid  = threadIdx.x;
    const int lane = tid & 63;
    const int wave = tid >> 6;
    const size_t m0 = (size_t)blockIdx.y * GBM;
    const size_t n0 = (size_t)blockIdx.x * GBN;
    const int wm = (wave >> 1) * 64;   // wave m-offset in tile
    const int wn = (wave & 1) * 32;    // wave n-offset in tile
    const int ar = tid >> 1;           // A stage: row 0..127
    const int ac = (tid & 1) * 16;     // A stage: col 0 or 16
    const int bn = lane;               // B stage: n 0..63
    const int bkg = wave;              // B stage: k-group 0..3 (k = bkg*8+j)
    const int fr = lane & 15;
    const int fg = lane >> 4;

    f32x4 acc[4][2] = {};

    for (int k0 = 0; k0 < K; k0 += GBK) {
        // global loads (f32) into registers
        float afl[16];
        const float* Ap = A + (m0 + ar) * (size_t)K + (k0 + ac);
        *(float4*)&afl[0]  = *(const float4*)(Ap + 0);
        *(float4*)&afl[4]  = *(const float4*)(Ap + 4);
        *(float4*)&afl[8]  = *(const float4*)(Ap + 8);
        *(float4*)&afl[12] = *(const float4*)(Ap + 12);
        float bfl[8];
        const float* Wp = W + (size_t)(k0 + bkg * 8) * N + (n0 + bn);
        #pragma unroll
        for (int j = 0; j < 8; ++j) bfl[j] = Wp[(size_t)j * N];

        __syncthreads();   // previous iteration's frag reads done
        s16x8 apk0, apk1, bpk;
        #pragma unroll
        for (int j = 0; j < 8; ++j) {
            apk0[j] = f2bf(afl[j]);
            apk1[j] = f2bf(afl[8 + j]);
            bpk[j]  = f2bf(bfl[j]);
        }
        *(s16x8*)&a_s[ar][ac]     = apk0;
        *(s16x8*)&a_s[ar][ac + 8] = apk1;
        *(s16x8*)&b_s[bn][bkg * 8] = bpk;   // transposed store: b_s[n][k]
        __syncthreads();

        s16x8 af[4], bfr[2];
        #pragma unroll
        for (int mi = 0; mi < 4; ++mi)
            af[mi] = *(const s16x8*)&a_s[wm + mi * 16 + fr][fg * 8];
        #pragma unroll
        for (int ni = 0; ni < 2; ++ni)
            bfr[ni] = *(const s16x8*)&b_s[wn + ni * 16 + fr][fg * 8];
        #pragma unroll
        for (int mi = 0; mi < 4; ++mi)
            #pragma unroll
            for (int ni = 0; ni < 2; ++ni)
                acc[mi][ni] = __builtin_amdgcn_mfma_f32_16x16x32_bf16(
                    af[mi], bfr[ni], acc[mi][ni], 0, 0, 0);
    }

    // epilogue: D[row][col]: col = lane&15, row = (lane>>4)*4 + reg  (m89 layout)
    #pragma unroll
    for (int mi = 0; mi < 4; ++mi) {
        #pragma unroll
        for (int ni = 0; ni < 2; ++ni) {
            size_t r = m0 + wm + mi * 16 + fg * 4;
            size_t c = n0 + wn + ni * 16 + fr;
            float bb = bias[c];
            #pragma unroll
            for (int rg = 0; rg < 4; ++rg) {
                float vv = acc[mi][ni][rg] + bb;
                if (act) vv = gelu_f(vv);
                C[(r + rg) * (size_t)N + c] = vv;
            }
        }
    }
}

// ---------------- fused flash attention with TXL relative shift ----------------
// score(s,t) = (q.k[t] + q.Qr[t + S-1-s]) / 8  for t <= s+M, else masked.
#define QB 32
#define KBT 32
#define AP 68   // padded f32 row stride (16B-aligned, spreads banks)

__global__ __launch_bounds__(256) void attn_kernel(
    const float* __restrict__ q, const float* __restrict__ k,
    const float* __restrict__ v, const float* __restrict__ Qr,
    float* __restrict__ ctx)
{
    __shared__ float q_s[QB][AP];
    __shared__ float k_s[KBT][AP];
    __shared__ float v_s[KBT][AP];
    __shared__ float qr_s[64][AP];          // shifted-Qr window: 63 rows used
    __shared__ float p_s[QB][KBT + 4];
    __shared__ float row_m[QB], row_l[QB], row_sc[QB];

    const int tid = threadIdx.x;
    const int q0  = blockIdx.x * QB;
    const int bh  = blockIdx.y;
    const int b   = bh >> 4;
    const int h   = bh & 15;
    const int hoff = h * DH;

    {   // load q rows (32 x 64) once
        int r = tid >> 3, cq = (tid & 7) * 8;
        const float* qp = q + ((size_t)(b * SS + q0 + r)) * DD + hoff + cq;
        *(float4*)&q_s[r][cq]     = *(const float4*)qp;
        *(float4*)&q_s[r][cq + 4] = *(const float4*)(qp + 4);
    }
    if (tid < QB) { row_m[tid] = -INFINITY; row_l[tid] = 0.0f; }

    float acc[8] = {0, 0, 0, 0, 0, 0, 0, 0};
    const int r_acc = tid >> 3;        // PV: owned row
    const int dg    = (tid & 7) * 8;   // PV: owned dim group
    const int t_end = q0 + QB + MEM;   // == max allowed t + 1 (<= TT)

    for (int t0 = 0; t0 < t_end; t0 += KBT) {
        __syncthreads();   // protect LDS reuse (also fences q_s/init on iter 0)
        {   // k/v tiles (32 x 64 each)
            int rr = tid >> 3, cq = (tid & 7) * 8;
            const float* kp = k + ((size_t)(b * TT + t0 + rr)) * DD + hoff + cq;
            const float* vp = v + ((size_t)(b * TT + t0 + rr)) * DD + hoff + cq;
            *(float4*)&k_s[rr][cq]     = *(const float4*)kp;
            *(float4*)&k_s[rr][cq + 4] = *(const float4*)(kp + 4);
            *(float4*)&v_s[rr][cq]     = *(const float4*)vp;
            *(float4*)&v_s[rr][cq + 4] = *(const float4*)(vp + 4);
        }
        {   // Qr window: u = t + S-1-s spans 63 rows for this (q-tile, k-tile)
            int i = tid >> 2, cq4 = (tid & 3) * 16;
            int u = t0 + SS - 1 - (q0 + QB - 1) + i;
            u = u < 0 ? 0 : (u > TT - 1 ? TT - 1 : u);   // clamp: masked region only
            const float* rp = Qr + (size_t)u * DD + hoff + cq4;
            *(float4*)&qr_s[i][cq4]      = *(const float4*)(rp);
            *(float4*)&qr_s[i][cq4 + 4]  = *(const float4*)(rp + 4);
            *(float4*)&qr_s[i][cq4 + 8]  = *(const float4*)(rp + 8);
            *(float4*)&qr_s[i][cq4 + 12] = *(const float4*)(rp + 12);
        }
        __syncthreads();

        const int t_l = tid & 31;
        #pragma unroll
        for (int ii = 0; ii < 4; ++ii) {
            const int r  = (tid >> 5) + 8 * ii;
            const int uo = t_l + (QB - 1) - r;   // 0..62
            float da = 0.0f, db = 0.0f;
            #pragma unroll
            for (int d = 0; d < DH; d += 4) {
                float4 qv = *(const float4*)&q_s[r][d];
                float4 kv = *(const float4*)&k_s[t_l][d];
                float4 rv = *(const float4*)&qr_s[uo][d];
                da += qv.x * kv.x + qv.y * kv.y + qv.z * kv.z + qv.w * kv.w;
                db += qv.x * rv.x + qv.y * rv.y + qv.z * rv.z + qv.w * rv.w;
            }
            const int t = t0 + t_l;
            const int s = q0 + r;
            p_s[r][t_l] = (t > s + MEM) ? -1e30f : (da + db) * 0.125f;
        }
        __syncthreads();

        if (tid < QB) {   // per-row running max
            float mx = -1e30f;
            for (int j = 0; j < KBT; ++j) mx = fmaxf(mx, p_s[tid][j]);
            float mo = row_m[tid];
            float mn = fmaxf(mo, mx);
            row_sc[tid] = __expf(mo - mn);
            row_m[tid]  = mn;
        }
        __syncthreads();

        {   // rescale acc, exponentiate scores
            float scl = row_sc[r_acc];
            #pragma unroll
            for (int j = 0; j < 8; ++j) acc[j] *= scl;
            #pragma unroll
            for (int ii = 0; ii < 4; ++ii) {
                const int r = (tid >> 5) + 8 * ii;
                p_s[r][t_l] = __expf(p_s[r][t_l] - row_m[r]);
            }
        }
        __syncthreads();

        if (tid < QB) {   // running denominator
            float sm = 0.0f;
            for (int j = 0; j < KBT; ++j) sm += p_s[tid][j];
            row_l[tid] = row_l[tid] * row_sc[tid] + sm;
        }
        // PV accumulate (reads p_s/v_s only; safe alongside row_l update)
        #pragma unroll 4
        for (int tl = 0; tl < KBT; ++tl) {
            float pp = p_s[r_acc][tl];
            #pragma unroll
            for (int j = 0; j < 8; ++j) acc[j] += pp * v_s[tl][dg + j];
        }
    }
    __syncthreads();   // make final row_l visible
    {
        float inv = 1.0f / row_l[r_acc];
        float* op = ctx + ((size_t)(b * SS + q0 + r_acc)) * DD + hoff + dg;
        float4 o0, o1;
        o0.x = acc[0] * inv; o0.y = acc[1] * inv; o0.z = acc[2] * inv; o0.w = acc[3] * inv;
        o1.x = acc[4] * inv; o1.y = acc[5] * inv; o1.z = acc[6] * inv; o1.w = acc[7] * inv;
        *(float4*)op       = o0;
        *(float4*)(op + 4) = o1;
    }
}

// ---------------- add + LayerNorm ----------------
__global__ __launch_bounds__(256) void addln_kernel(
    const float* __restrict__ a, const float* __restrict__ b,
    const float* __restrict__ g, const float* __restrict__ be,
    float* __restrict__ out)
{
    __shared__ float red[8];
    const int row = blockIdx.x;
    const int tid = threadIdx.x;
    const size_t base = (size_t)row * DD;
    const int c = tid * 4;
    float4 xa = *(const float4*)(a + base + c);
    float4 xb = *(const float4*)(b + base + c);
    float x0 = xa.x + xb.x, x1 = xa.y + xb.y, x2 = xa.z + xb.z, x3 = xa.w + xb.w;
    float s  = x0 + x1 + x2 + x3;
    float sq = x0 * x0 + x1 * x1 + x2 * x2 + x3 * x3;
    #pragma unroll
    for (int o = 32; o > 0; o >>= 1) {
        s  += __shfl_down(s, o, 64);
        sq += __shfl_down(sq, o, 64);
    }
    const int wv = tid >> 6;
    if ((tid & 63) == 0) { red[wv * 2] = s; red[wv * 2 + 1] = sq; }
    __syncthreads();
    float ts = red[0] + red[2] + red[4] + red[6];
    float tq = red[1] + red[3] + red[5] + red[7];
    float mu  = ts * (1.0f / DD);
    float var = tq * (1.0f / DD) - mu * mu;
    float rs  = rsqrtf(var + 1e-5f);
    float4 gv = *(const float4*)(g + c);
    float4 bv = *(const float4*)(be + c);
    float4 o4;
    o4.x = (x0 - mu) * rs * gv.x + bv.x;
    o4.y = (x1 - mu) * rs * gv.y + bv.y;
    o4.z = (x2 - mu) * rs * gv.z + bv.z;
    o4.w = (x3 - mu) * rs * gv.w + bv.w;
    *(float4*)(out + base + c) = o4;
}

// ---------------- embedding gather * sqrt(D) ----------------
__global__ __launch_bounds__(256) void embed_kernel(
    const int* __restrict__ inp, const float* __restrict__ emb, float* __restrict__ x)
{
    const int row = blockIdx.x;
    const int c = threadIdx.x * 4;
    const int idx = inp[row];
    float4 vv = *(const float4*)(emb + (size_t)idx * DD + c);
    vv.x *= 32.0f; vv.y *= 32.0f; vv.z *= 32.0f; vv.w *= 32.0f;
    *(float4*)(x + (size_t)row * DD + c) = vv;
}

// ---------------- concat mems[l] and x into x_tilde ----------------
__global__ __launch_bounds__(256) void concat_kernel(
    const float* __restrict__ mems_l, const float* __restrict__ x, float* __restrict__ xt)
{
    size_t i = ((size_t)blockIdx.x * 256 + threadIdx.x) * 4;
    size_t bt = i / DD;
    int d = (int)(i - bt * DD);
    int b = (int)(bt / TT);
    int t = (int)(bt - (size_t)b * TT);
    float4 vv;
    if (t < MEM) vv = *(const float4*)(mems_l + ((size_t)(b * MEM + t)) * DD + d);
    else         vv = *(const float4*)(x + ((size_t)(b * SS + (t - MEM))) * DD + d);
    *(float4*)(xt + i) = vv;
}

// ---------------- reversed sinusoidal position encoding ----------------
__global__ __launch_bounds__(256) void relenc_kernel(float* __restrict__ re)
{
    const int u = blockIdx.x;          // rel_enc row
    const int p = TT - 1 - u;          // reversed position
    const int i0 = threadIdx.x * 4;
    #pragma unroll
    for (int j = 0; j < 4; ++j) {
        int i = i0 + j;
        float ex   = (float)(2 * (i >> 1)) * (1.0f / DD);
        float invf = __expf(-ex * 9.210340371976184f);   // 10000^-ex
        float ang  = (float)p * invf;
        re[(size_t)u * DD + i] = (i & 1) ? cosf(ang) : sinf(ang);
    }
}

extern "C" void kernel_launch(void* const* d_in, const int* in_sizes, int n_in,
                              void* d_out, int out_size, void* d_ws, size_t ws_size,
                              hipStream_t stream)
{
    const int*   inp  = (const int*)d_in[0];
    const float* mems = (const float*)d_in[1];
    const float* emb  = (const float*)d_in[2];
    const float* Wq   = (const float*)d_in[3];
    const float* bq   = (const float*)d_in[4];
    const float* Wke  = (const float*)d_in[5];
    const float* bke  = (const float*)d_in[6];
    const float* Wkr  = (const float*)d_in[7];
    const float* bkr  = (const float*)d_in[8];
    const float* Wv   = (const float*)d_in[9];
    const float* bv   = (const float*)d_in[10];
    const float* Wo   = (const float*)d_in[11];
    const float* bo   = (const float*)d_in[12];
    const float* ln1g = (const float*)d_in[13];
    const float* ln1b = (const float*)d_in[14];
    const float* W1   = (const float*)d_in[15];
    const float* b1   = (const float*)d_in[16];
    const float* W2   = (const float*)d_in[17];
    const float* b2   = (const float*)d_in[18];
    const float* ln2g = (const float*)d_in[19];
    const float* ln2b = (const float*)d_in[20];
    const float* Wh   = (const float*)d_in[21];
    const float* bh   = (const float*)d_in[22];
    const float* Wf   = (const float*)d_in[23];
    const float* bfb  = (const float*)d_in[24];

    float* ws = (float*)d_ws;
    size_t o = 0;
    float* rel  = ws + o; o += (size_t)TT * DD;
    float* x    = ws + o; o += (size_t)BB * SS * DD;
    float* xt   = ws + o; o += (size_t)BB * TT * DD;
    float* qb   = ws + o; o += (size_t)BB * SS * DD;
    float* kb   = ws + o; o += (size_t)BB * TT * DD;
    float* vb   = ws + o; o += (size_t)BB * TT * DD;
    float* Qrb  = ws + o; o += (size_t)TT * DD;
    float* ctxb = ws + o; o += (size_t)BB * SS * DD;
    float* ao   = ws + o; o += (size_t)BB * SS * DD;
    float* h1   = ws + o; o += (size_t)BB * SS * DD;
    float* ff1  = ws + o; o += (size_t)BB * SS * DD;
    float* ff2  = ws + o; o += (size_t)BB * SS * DD;

    relenc_kernel<<<TT, 256, 0, stream>>>(rel);
    embed_kernel<<<BB * SS, 256, 0, stream>>>(inp, emb, x);

    const dim3 gD(DD / GBN, (BB * SS) / GBM);   // (16,16)
    const dim3 gT(DD / GBN, (BB * TT) / GBM);   // (16,32)
    const dim3 gR(DD / GBN, TT / GBM);          // (16,16)

    for (int l = 0; l < LL; ++l) {
        const size_t wo  = (size_t)l * DD * DD;
        const size_t bo_ = (size_t)l * DD;
        concat_kernel<<<(BB * TT * DD / 4) / 256, 256, 0, stream>>>(
            mems + (size_t)l * BB * MEM * DD, x, xt);
        gemm_kernel<<<gD, 256, 0, stream>>>(x,   Wq  + wo, bq  + bo_, qb,  DD, DD, 0);
        gemm_kernel<<<gT, 256, 0, stream>>>(xt,  Wke + wo, bke + bo_, kb,  DD, DD, 0);
        gemm_kernel<<<gT, 256, 0, stream>>>(xt,  Wv  + wo, bv  + bo_, vb,  DD, DD, 0);
        gemm_kernel<<<gR, 256, 0, stream>>>(rel, Wkr + wo, bkr + bo_, Qrb, DD, DD, 0);
        attn_kernel<<<dim3(SS / QB, BB * NH), 256, 0, stream>>>(qb, kb, vb, Qrb, ctxb);
        gemm_kernel<<<gD, 256, 0, stream>>>(ctxb, Wo + wo, bo + bo_, ao, DD, DD, 0);
        addln_kernel<<<BB * SS, 256, 0, stream>>>(x, ao, ln1g + bo_, ln1b + bo_, h1);
        gemm_kernel<<<gD, 256, 0, stream>>>(h1,  W1 + wo, b1 + bo_, ff1, DD, DD, 1);
        gemm_kernel<<<gD, 256, 0, stream>>>(ff1, W2 + wo, b2 + bo_, ff2, DD, DD, 0);
        addln_kernel<<<BB * SS, 256, 0, stream>>>(h1, ff2, ln2g + bo_, ln2b + bo_, x);
    }

    // final head: reuse qb as gelu(x @ Wh + bh)
    gemm_kernel<<<gD, 256, 0, stream>>>(x, Wh, bh, qb, DD, DD, 1);
    gemm_kernel<<<dim3(VV / GBN, (BB * SS) / GBM), 256, 0, stream>>>(
        qb, Wf, bfb, (float*)d_out, VV, DD, 0);
}

// Round 2
// 6594.392 us; speedup vs baseline: 1.0002x; 1.0002x over previous
//
#include <hip/hip_runtime.h>
#include <hip/hip_bf16.h>
#include <math.h>

typedef __attribute__((ext_vector_type(4))) float f32x4;
typedef __attribute__((ext_vector_type(8))) short s16x8;

#define BB 2
#define SS 1024
#define MEM 1024
#define DD 1024
#define LL 4
#define VV 32000
#define TT 2048
#define NH 16
#define DH 64

__device__ __forceinline__ short f2bf(float f) {
    unsigned u = __float_as_uint(f);
    u += 0x7fffu + ((u >> 16) & 1u);   // round-to-nearest-even
    return (short)(u >> 16);
}

__device__ __forceinline__ float gelu_f(float x) {
    return 0.5f * x * (1.0f + erff(x * 0.70710678118654752f));
}

// ---------------- GEMM: C(M,N) = act(A(M,K) @ W(K,N) + bias) ----------------
// A, W, C are f32 in global memory; staged into LDS as bf16, MFMA 16x16x32.
// Tile: BM=128, BN=64, BK=32. 4 waves, each owns a 64x32 sub-tile (4x2 frags).
#define GBM 128
#define GBN 64
#define GBK 32
#define GLD 40   // LDS row stride in shorts (32 + 8 pad -> 2-way-free frag reads)

__global__ __launch_bounds__(256) void gemm_kernel(
    const float* __restrict__ A, const float* __restrict__ W,
    const float* __restrict__ bias, float* __restrict__ C,
    int N, int K, int act)
{
    __shared__ short a_s[GBM][GLD];
    __shared__ short b_s[GBN][GLD];
    const int tid  = threadIdx.x;
    const int lane = tid & 63;
    const int wave = tid >> 6;
    const size_t m0 = (size_t)blockIdx.y * GBM;
    const size_t n0 = (size_t)blockIdx.x * GBN;
    const int wm = (wave >> 1) * 64;   // wave m-offset in tile
    const int wn = (wave & 1) * 32;    // wave n-offset in tile
    const int ar = tid >> 1;           // A stage: row 0..127
    const int ac = (tid & 1) * 16;     // A stage: col 0 or 16
    const int bn = lane;               // B stage: n 0..63
    const int bkg = wave;              // B stage: k-group 0..3 (k = bkg*8+j)
    const int fr = lane & 15;
    const int fg = lane >> 4;

    f32x4 acc[4][2] = {};

    for (int k0 = 0; k0 < K; k0 += GBK) {
        // global loads (f32) into registers
        float afl[16];
        const float* Ap = A + (m0 + ar) * (size_t)K + (k0 + ac);
        *(float4*)&afl[0]  = *(const float4*)(Ap + 0);
        *(float4*)&afl[4]  = *(const float4*)(Ap + 4);
        *(float4*)&afl[8]  = *(const float4*)(Ap + 8);
        *(float4*)&afl[12] = *(const float4*)(Ap + 12);
        float bfl[8];
        const float* Wp = W + (size_t)(k0 + bkg * 8) * N + (n0 + bn);
        #pragma unroll
        for (int j = 0; j < 8; ++j) bfl[j] = Wp[(size_t)j * N];

        __syncthreads();   // previous iteration's frag reads done
        s16x8 apk0, apk1, bpk;
        #pragma unroll
        for (int j = 0; j < 8; ++j) {
            apk0[j] = f2bf(afl[j]);
            apk1[j] = f2bf(afl[8 + j]);
            bpk[j]  = f2bf(bfl[j]);
        }
        *(s16x8*)&a_s[ar][ac]     = apk0;
        *(s16x8*)&a_s[ar][ac + 8] = apk1;
        *(s16x8*)&b_s[bn][bkg * 8] = bpk;   // transposed store: b_s[n][k]
        __syncthreads();

        s16x8 af[4], bfr[2];
        #pragma unroll
        for (int mi = 0; mi < 4; ++mi)
            af[mi] = *(const s16x8*)&a_s[wm + mi * 16 + fr][fg * 8];
        #pragma unroll
        for (int ni = 0; ni < 2; ++ni)
            bfr[ni] = *(const s16x8*)&b_s[wn + ni * 16 + fr][fg * 8];
        #pragma unroll
        for (int mi = 0; mi < 4; ++mi)
            #pragma unroll
            for (int ni = 0; ni < 2; ++ni)
                acc[mi][ni] = __builtin_amdgcn_mfma_f32_16x16x32_bf16(
                    af[mi], bfr[ni], acc[mi][ni], 0, 0, 0);
    }

    // epilogue: D[row][col]: col = lane&15, row = (lane>>4)*4 + reg  (m89 layout)
    #pragma unroll
    for (int mi = 0; mi < 4; ++mi) {
        #pragma unroll
        for (int ni = 0; ni < 2; ++ni) {
            size_t r = m0 + wm + mi * 16 + fg * 4;
            size_t c = n0 + wn + ni * 16 + fr;
            float bb = bias[c];
            #pragma unroll
            for (int rg = 0; rg < 4; ++rg) {
                float vv = acc[mi][ni][rg] + bb;
                if (act) vv = gelu_f(vv);
                C[(r + rg) * (size_t)N + c] = vv;
            }
        }
    }
}

// ---------------- fused flash attention with TXL relative shift ----------------
// score(s,t) = (q.k[t] + q.Qr[t + S-1-s]) / 8  for t <= s+M, else masked.
#define QB 32
#define KBT 32
#define AP 68   // padded f32 row stride (16B-aligned, spreads banks)

__global__ __launch_bounds__(256) void attn_kernel(
    const float* __restrict__ q, const float* __restrict__ k,
    const float* __restrict__ v, const float* __restrict__ Qr,
    float* __restrict__ ctx)
{
    __shared__ float q_s[QB][AP];
    __shared__ float k_s[KBT][AP];
    __shared__ float v_s[KBT][AP];
    __shared__ float qr_s[64][AP];          // shifted-Qr window: 63 rows used
    __shared__ float p_s[QB][KBT + 4];
    __shared__ float row_m[QB], row_l[QB], row_sc[QB];

    const int tid = threadIdx.x;
    const int q0  = blockIdx.x * QB;
    const int bh  = blockIdx.y;
    const int b   = bh >> 4;
    const int h   = bh & 15;
    const int hoff = h * DH;

    {   // load q rows (32 x 64) once
        int r = tid >> 3, cq = (tid & 7) * 8;
        const float* qp = q + ((size_t)(b * SS + q0 + r)) * DD + hoff + cq;
        *(float4*)&q_s[r][cq]     = *(const float4*)qp;
        *(float4*)&q_s[r][cq + 4] = *(const float4*)(qp + 4);
    }
    if (tid < QB) { row_m[tid] = -INFINITY; row_l[tid] = 0.0f; }

    float acc[8] = {0, 0, 0, 0, 0, 0, 0, 0};
    const int r_acc = tid >> 3;        // PV: owned row
    const int dg    = (tid & 7) * 8;   // PV: owned dim group
    const int t_end = q0 + QB + MEM;   // == max allowed t + 1 (<= TT)

    for (int t0 = 0; t0 < t_end; t0 += KBT) {
        __syncthreads();   // protect LDS reuse (also fences q_s/init on iter 0)
        {   // k/v tiles (32 x 64 each)
            int rr = tid >> 3, cq = (tid & 7) * 8;
            const float* kp = k + ((size_t)(b * TT + t0 + rr)) * DD + hoff + cq;
            const float* vp = v + ((size_t)(b * TT + t0 + rr)) * DD + hoff + cq;
            *(float4*)&k_s[rr][cq]     = *(const float4*)kp;
            *(float4*)&k_s[rr][cq + 4] = *(const float4*)(kp + 4);
            *(float4*)&v_s[rr][cq]     = *(const float4*)vp;
            *(float4*)&v_s[rr][cq + 4] = *(const float4*)(vp + 4);
        }
        {   // Qr window: u = t + S-1-s spans 63 rows for this (q-tile, k-tile)
            int i = tid >> 2, cq4 = (tid & 3) * 16;
            int u = t0 + SS - 1 - (q0 + QB - 1) + i;
            u = u < 0 ? 0 : (u > TT - 1 ? TT - 1 : u);   // clamp: masked region only
            const float* rp = Qr + (size_t)u * DD + hoff + cq4;
            *(float4*)&qr_s[i][cq4]      = *(const float4*)(rp);
            *(float4*)&qr_s[i][cq4 + 4]  = *(const float4*)(rp + 4);
            *(float4*)&qr_s[i][cq4 + 8]  = *(const float4*)(rp + 8);
            *(float4*)&qr_s[i][cq4 + 12] = *(const float4*)(rp + 12);
        }
        __syncthreads();

        const int t_l = tid & 31;
        #pragma unroll
        for (int ii = 0; ii < 4; ++ii) {
            const int r  = (tid >> 5) + 8 * ii;
            const int uo = t_l + (QB - 1) - r;   // 0..62
            float da = 0.0f, db = 0.0f;
            #pragma unroll
            for (int d = 0; d < DH; d += 4) {
                float4 qv = *(const float4*)&q_s[r][d];
                float4 kv = *(const float4*)&k_s[t_l][d];
                float4 rv = *(const float4*)&qr_s[uo][d];
                da += qv.x * kv.x + qv.y * kv.y + qv.z * kv.z + qv.w * kv.w;
                db += qv.x * rv.x + qv.y * rv.y + qv.z * rv.z + qv.w * rv.w;
            }
            const int t = t0 + t_l;
            const int s = q0 + r;
            p_s[r][t_l] = (t > s + MEM) ? -1e30f : (da + db) * 0.125f;
        }
        __syncthreads();

        if (tid < QB) {   // per-row running max
            float mx = -1e30f;
            for (int j = 0; j < KBT; ++j) mx = fmaxf(mx, p_s[tid][j]);
            float mo = row_m[tid];
            float mn = fmaxf(mo, mx);
            row_sc[tid] = __expf(mo - mn);
            row_m[tid]  = mn;
        }
        __syncthreads();

        {   // rescale acc, exponentiate scores
            float scl = row_sc[r_acc];
            #pragma unroll
            for (int j = 0; j < 8; ++j) acc[j] *= scl;
            #pragma unroll
            for (int ii = 0; ii < 4; ++ii) {
                const int r = (tid >> 5) + 8 * ii;
                p_s[r][t_l] = __expf(p_s[r][t_l] - row_m[r]);
            }
        }
        __syncthreads();

        if (tid < QB) {   // running denominator
            float sm = 0.0f;
            for (int j = 0; j < KBT; ++j) sm += p_s[tid][j];
            row_l[tid] = row_l[tid] * row_sc[tid] + sm;
        }
        // PV accumulate (reads p_s/v_s only; safe alongside row_l update)
        #pragma unroll 4
        for (int tl = 0; tl < KBT; ++tl) {
            float pp = p_s[r_acc][tl];
            #pragma unroll
            for (int j = 0; j < 8; ++j) acc[j] += pp * v_s[tl][dg + j];
        }
    }
    __syncthreads();   // make final row_l visible
    {
        float inv = 1.0f / row_l[r_acc];
        float* op = ctx + ((size_t)(b * SS + q0 + r_acc)) * DD + hoff + dg;
        float4 o0, o1;
        o0.x = acc[0] * inv; o0.y = acc[1] * inv; o0.z = acc[2] * inv; o0.w = acc[3] * inv;
        o1.x = acc[4] * inv; o1.y = acc[5] * inv; o1.z = acc[6] * inv; o1.w = acc[7] * inv;
        *(float4*)op       = o0;
        *(float4*)(op + 4) = o1;
    }
}

// ---------------- add + LayerNorm ----------------
__global__ __launch_bounds__(256) void addln_kernel(
    const float* __restrict__ a, const float* __restrict__ b,
    const float* __restrict__ g, const float* __restrict__ be,
    float* __restrict__ out)
{
    __shared__ float red[8];
    const int row = blockIdx.x;
    const int tid = threadIdx.x;
    const size_t base = (size_t)row * DD;
    const int c = tid * 4;
    float4 xa = *(const float4*)(a + base + c);
    float4 xb = *(const float4*)(b + base + c);
    float x0 = xa.x + xb.x, x1 = xa.y + xb.y, x2 = xa.z + xb.z, x3 = xa.w + xb.w;
    float s  = x0 + x1 + x2 + x3;
    float sq = x0 * x0 + x1 * x1 + x2 * x2 + x3 * x3;
    #pragma unroll
    for (int o = 32; o > 0; o >>= 1) {
        s  += __shfl_down(s, o, 64);
        sq += __shfl_down(sq, o, 64);
    }
    const int wv = tid >> 6;
    if ((tid & 63) == 0) { red[wv * 2] = s; red[wv * 2 + 1] = sq; }
    __syncthreads();
    float ts = red[0] + red[2] + red[4] + red[6];
    float tq = red[1] + red[3] + red[5] + red[7];
    float mu  = ts * (1.0f / DD);
    float var = tq * (1.0f / DD) - mu * mu;
    float rs  = rsqrtf(var + 1e-5f);
    float4 gv = *(const float4*)(g + c);
    float4 bv = *(const float4*)(be + c);
    float4 o4;
    o4.x = (x0 - mu) * rs * gv.x + bv.x;
    o4.y = (x1 - mu) * rs * gv.y + bv.y;
    o4.z = (x2 - mu) * rs * gv.z + bv.z;
    o4.w = (x3 - mu) * rs * gv.w + bv.w;
    *(float4*)(out + base + c) = o4;
}

// ---------------- embedding gather * sqrt(D) ----------------
__global__ __launch_bounds__(256) void embed_kernel(
    const int* __restrict__ inp, const float* __restrict__ emb, float* __restrict__ x)
{
    const int row = blockIdx.x;
    const int c = threadIdx.x * 4;
    const int idx = inp[row];
    float4 vv = *(const float4*)(emb + (size_t)idx * DD + c);
    vv.x *= 32.0f; vv.y *= 32.0f; vv.z *= 32.0f; vv.w *= 32.0f;
    *(float4*)(x + (size_t)row * DD + c) = vv;
}

// ---------------- concat mems[l] and x into x_tilde ----------------
__global__ __launch_bounds__(256) void concat_kernel(
    const float* __restrict__ mems_l, const float* __restrict__ x, float* __restrict__ xt)
{
    size_t i = ((size_t)blockIdx.x * 256 + threadIdx.x) * 4;
    size_t bt = i / DD;
    int d = (int)(i - bt * DD);
    int b = (int)(bt / TT);
    int t = (int)(bt - (size_t)b * TT);
    float4 vv;
    if (t < MEM) vv = *(const float4*)(mems_l + ((size_t)(b * MEM + t)) * DD + d);
    else         vv = *(const float4*)(x + ((size_t)(b * SS + (t - MEM))) * DD + d);
    *(float4*)(xt + i) = vv;
}

// ---------------- reversed sinusoidal position encoding ----------------
__global__ __launch_bounds__(256) void relenc_kernel(float* __restrict__ re)
{
    const int u = blockIdx.x;          // rel_enc row
    const int p = TT - 1 - u;          // reversed position
    const int i0 = threadIdx.x * 4;
    #pragma unroll
    for (int j = 0; j < 4; ++j) {
        int i = i0 + j;
        float ex   = (float)(2 * (i >> 1)) * (1.0f / DD);
        float invf = __expf(-ex * 9.210340371976184f);   // 10000^-ex
        float ang  = (float)p * invf;
        re[(size_t)u * DD + i] = (i & 1) ? cosf(ang) : sinf(ang);
    }
}

extern "C" void kernel_launch(void* const* d_in, const int* in_sizes, int n_in,
                              void* d_out, int out_size, void* d_ws, size_t ws_size,
                              hipStream_t stream)
{
    const int*   inp  = (const int*)d_in[0];
    const float* mems = (const float*)d_in[1];
    const float* emb  = (const float*)d_in[2];
    const float* Wq   = (const float*)d_in[3];
    const float* bq   = (const float*)d_in[4];
    const float* Wke  = (const float*)d_in[5];
    const float* bke  = (const float*)d_in[6];
    const float* Wkr  = (const float*)d_in[7];
    const float* bkr  = (const float*)d_in[8];
    const float* Wv   = (const float*)d_in[9];
    const float* bv   = (const float*)d_in[10];
    const float* Wo   = (const float*)d_in[11];
    const float* bo   = (const float*)d_in[12];
    const float* ln1g = (const float*)d_in[13];
    const float* ln1b = (const float*)d_in[14];
    const float* W1   = (const float*)d_in[15];
    const float* b1   = (const float*)d_in[16];
    const float* W2   = (const float*)d_in[17];
    const float* b2   = (const float*)d_in[18];
    const float* ln2g = (const float*)d_in[19];
    const float* ln2b = (const float*)d_in[20];
    const float* Wh   = (const float*)d_in[21];
    const float* bh   = (const float*)d_in[22];
    const float* Wf   = (const float*)d_in[23];
    const float* bfb  = (const float*)d_in[24];

    float* ws = (float*)d_ws;
    size_t o = 0;
    float* rel  = ws + o; o += (size_t)TT * DD;
    float* x    = ws + o; o += (size_t)BB * SS * DD;
    float* xt   = ws + o; o += (size_t)BB * TT * DD;
    float* qb   = ws + o; o += (size_t)BB * SS * DD;
    float* kb   = ws + o; o += (size_t)BB * TT * DD;
    float* vb   = ws + o; o += (size_t)BB * TT * DD;
    float* Qrb  = ws + o; o += (size_t)TT * DD;
    float* ctxb = ws + o; o += (size_t)BB * SS * DD;
    float* ao   = ws + o; o += (size_t)BB * SS * DD;
    float* h1   = ws + o; o += (size_t)BB * SS * DD;
    float* ff1  = ws + o; o += (size_t)BB * SS * DD;
    float* ff2  = ws + o; o += (size_t)BB * SS * DD;

    relenc_kernel<<<TT, 256, 0, stream>>>(rel);
    embed_kernel<<<BB * SS, 256, 0, stream>>>(inp, emb, x);

    const dim3 gD(DD / GBN, (BB * SS) / GBM);   // (16,16)
    const dim3 gT(DD / GBN, (BB * TT) / GBM);   // (16,32)
    const dim3 gR(DD / GBN, TT / GBM);          // (16,16)

    for (int l = 0; l < LL; ++l) {
        const size_t wo  = (size_t)l * DD * DD;
        const size_t bo_ = (size_t)l * DD;
        concat_kernel<<<(BB * TT * DD / 4) / 256, 256, 0, stream>>>(
            mems + (size_t)l * BB * MEM * DD, x, xt);
        gemm_kernel<<<gD, 256, 0, stream>>>(x,   Wq  + wo, bq  + bo_, qb,  DD, DD, 0);
        gemm_kernel<<<gT, 256, 0, stream>>>(xt,  Wke + wo, bke + bo_, kb,  DD, DD, 0);
        gemm_kernel<<<gT, 256, 0, stream>>>(xt,  Wv  + wo, bv  + bo_, vb,  DD, DD, 0);
        gemm_kernel<<<gR, 256, 0, stream>>>(rel, Wkr + wo, bkr + bo_, Qrb, DD, DD, 0);
        attn_kernel<<<dim3(SS / QB, BB * NH), 256, 0, stream>>>(qb, kb, vb, Qrb, ctxb);
        gemm_kernel<<<gD, 256, 0, stream>>>(ctxb, Wo + wo, bo + bo_, ao, DD, DD, 0);
        addln_kernel<<<BB * SS, 256, 0, stream>>>(x, ao, ln1g + bo_, ln1b + bo_, h1);
        gemm_kernel<<<gD, 256, 0, stream>>>(h1,  W1 + wo, b1 + bo_, ff1, DD, DD, 1);
        gemm_kernel<<<gD, 256, 0, stream>>>(ff1, W2 + wo, b2 + bo_, ff2, DD, DD, 0);
        addln_kernel<<<BB * SS, 256, 0, stream>>>(h1, ff2, ln2g + bo_, ln2b + bo_, x);
    }

    // final head: reuse qb as gelu(x @ Wh + bh)
    gemm_kernel<<<gD, 256, 0, stream>>>(x, Wh, bh, qb, DD, DD, 1);
    gemm_kernel<<<dim3(VV / GBN, (BB * SS) / GBM), 256, 0, stream>>>(
        qb, Wf, bfb, (float*)d_out, VV, DD, 0);
}

// Round 3
// 2087.814 us; speedup vs baseline: 3.1591x; 3.1585x over previous
//
#include <hip/hip_runtime.h>
#include <hip/hip_bf16.h>
#include <math.h>

typedef __attribute__((ext_vector_type(4))) float f32x4;
typedef __attribute__((ext_vector_type(8))) short s16x8;
typedef __attribute__((ext_vector_type(4))) short s16x4;

#define BB 2
#define SS 1024
#define MEM 1024
#define DD 1024
#define LL 4
#define VV 32000
#define TT 2048
#define NH 16
#define DH 64

__device__ __forceinline__ short f2bf(float f) {
    unsigned u = __float_as_uint(f);
    u += 0x7fffu + ((u >> 16) & 1u);   // round-to-nearest-even
    return (short)(u >> 16);
}

__device__ __forceinline__ float gelu_f(float x) {
    return 0.5f * x * (1.0f + erff(x * 0.70710678118654752f));
}

// ---------------- GEMM: C(M,N) = act(A(M,K) @ W(K,N) + bias) ----------------
#define GBM 128
#define GBN 64
#define GBK 32
#define GLD 40

__global__ __launch_bounds__(256) void gemm_kernel(
    const float* __restrict__ A, const float* __restrict__ W,
    const float* __restrict__ bias, float* __restrict__ C,
    int N, int K, int act)
{
    __shared__ short a_s[GBM][GLD];
    __shared__ short b_s[GBN][GLD];
    const int tid  = threadIdx.x;
    const int lane = tid & 63;
    const int wave = tid >> 6;
    const size_t m0 = (size_t)blockIdx.y * GBM;
    const size_t n0 = (size_t)blockIdx.x * GBN;
    const int wm = (wave >> 1) * 64;
    const int wn = (wave & 1) * 32;
    const int ar = tid >> 1;
    const int ac = (tid & 1) * 16;
    const int bn = lane;
    const int bkg = wave;
    const int fr = lane & 15;
    const int fg = lane >> 4;

    f32x4 acc[4][2] = {};

    for (int k0 = 0; k0 < K; k0 += GBK) {
        float afl[16];
        const float* Ap = A + (m0 + ar) * (size_t)K + (k0 + ac);
        *(float4*)&afl[0]  = *(const float4*)(Ap + 0);
        *(float4*)&afl[4]  = *(const float4*)(Ap + 4);
        *(float4*)&afl[8]  = *(const float4*)(Ap + 8);
        *(float4*)&afl[12] = *(const float4*)(Ap + 12);
        float bfl[8];
        const float* Wp = W + (size_t)(k0 + bkg * 8) * N + (n0 + bn);
        #pragma unroll
        for (int j = 0; j < 8; ++j) bfl[j] = Wp[(size_t)j * N];

        __syncthreads();
        s16x8 apk0, apk1, bpk;
        #pragma unroll
        for (int j = 0; j < 8; ++j) {
            apk0[j] = f2bf(afl[j]);
            apk1[j] = f2bf(afl[8 + j]);
            bpk[j]  = f2bf(bfl[j]);
        }
        *(s16x8*)&a_s[ar][ac]     = apk0;
        *(s16x8*)&a_s[ar][ac + 8] = apk1;
        *(s16x8*)&b_s[bn][bkg * 8] = bpk;
        __syncthreads();

        s16x8 af[4], bfr[2];
        #pragma unroll
        for (int mi = 0; mi < 4; ++mi)
            af[mi] = *(const s16x8*)&a_s[wm + mi * 16 + fr][fg * 8];
        #pragma unroll
        for (int ni = 0; ni < 2; ++ni)
            bfr[ni] = *(const s16x8*)&b_s[wn + ni * 16 + fr][fg * 8];
        #pragma unroll
        for (int mi = 0; mi < 4; ++mi)
            #pragma unroll
            for (int ni = 0; ni < 2; ++ni)
                acc[mi][ni] = __builtin_amdgcn_mfma_f32_16x16x32_bf16(
                    af[mi], bfr[ni], acc[mi][ni], 0, 0, 0);
    }

    #pragma unroll
    for (int mi = 0; mi < 4; ++mi) {
        #pragma unroll
        for (int ni = 0; ni < 2; ++ni) {
            size_t r = m0 + wm + mi * 16 + fg * 4;
            size_t c = n0 + wn + ni * 16 + fr;
            float bb = bias[c];
            #pragma unroll
            for (int rg = 0; rg < 4; ++rg) {
                float vv = acc[mi][ni][rg] + bb;
                if (act) vv = gelu_f(vv);
                C[(r + rg) * (size_t)N + c] = vv;
            }
        }
    }
}

// ---------------- MFMA flash attention with TXL relative shift ----------------
// Per block: 32 q rows of one (b,h). Per 32-key tile:
//   a_t = q @ k^T (32x32 MFMA), b_t = q @ QrWin^T (32x64 MFMA, skewed band),
//   score[r][t] = (a_t[r][t] + b_t[r][t+31-r])/8, online softmax (f32),
//   acc += P @ V (MFMA, V transposed in LDS with XOR t-block swizzle).
__global__ __launch_bounds__(256) void attn_kernel(
    const float* __restrict__ q, const float* __restrict__ k,
    const float* __restrict__ v, const float* __restrict__ Qr,
    float* __restrict__ ctx)
{
    __shared__ short q_s[32][72];
    __shared__ short k_s[32][72];
    __shared__ short qr_s[64][72];
    __shared__ short vT_s[64][40];   // [d][t^X], X = ((d>>3)&3)<<3
    __shared__ float a_t[32][37];    // odd stride: conflict-free softmax reads
    __shared__ float b_t[32][68];
    __shared__ short p_s[32][40];
    __shared__ float row_m[32], row_l[32], row_sc[32];

    const int tid  = threadIdx.x;
    const int id   = blockIdx.x;
    const int bh   = id & 31;
    const int qi   = ((id >> 5) + bh) & 31;   // balance tile-count across CUs
    const int q0   = qi * 32;
    const int b    = bh >> 4;
    const int h    = bh & 15;
    const int hoff = h * DH;

    const int lane = tid & 63;
    const int wave = tid >> 6;
    const int fr   = lane & 15;
    const int fg   = lane >> 4;
    const int mi   = wave >> 1;          // q-frag row /16
    const int nqk  = wave & 1;           // QK col frag
    const int nf0  = (wave & 1) * 2;     // QR/PV col frag base
    // staging maps
    const int tk  = tid >> 3;            // 0..31
    const int ck  = (tid & 7) * 8;       // 0..56
    const int iq  = tid >> 2;            // 0..63
    const int cq4 = (tid & 3) * 16;
    // softmax map
    const int sr  = tid >> 3;
    const int sc0 = (tid & 7) * 4;

    {   // stage q once (bf16)
        const float* qp = q + ((size_t)(b * SS + q0 + tk)) * DD + hoff + ck;
        float4 a0 = *(const float4*)qp;
        float4 a1 = *(const float4*)(qp + 4);
        s16x8 pk;
        pk[0]=f2bf(a0.x); pk[1]=f2bf(a0.y); pk[2]=f2bf(a0.z); pk[3]=f2bf(a0.w);
        pk[4]=f2bf(a1.x); pk[5]=f2bf(a1.y); pk[6]=f2bf(a1.z); pk[7]=f2bf(a1.w);
        *(s16x8*)&q_s[tk][ck] = pk;
    }
    if (tid < 32) { row_m[tid] = -INFINITY; row_l[tid] = 0.0f; }

    const int t_end   = q0 + 32 + MEM;
    const int u0base  = SS - 1 - (q0 + 31);   // u = t0 + u0base + i

    float4 kf0, kf1, vf0, vf1, rf0, rf1, rf2, rf3;   // prefetch regs
    auto loadT = [&](int t0) {
        const float* kp = k + ((size_t)(b * TT + t0 + tk)) * DD + hoff + ck;
        const float* vp = v + ((size_t)(b * TT + t0 + tk)) * DD + hoff + ck;
        kf0 = *(const float4*)kp;  kf1 = *(const float4*)(kp + 4);
        vf0 = *(const float4*)vp;  vf1 = *(const float4*)(vp + 4);
        int u = t0 + u0base + iq;
        u = u < 0 ? 0 : (u > TT - 1 ? TT - 1 : u);   // clamped rows are masked-only
        const float* rp = Qr + (size_t)u * DD + hoff + cq4;
        rf0 = *(const float4*)rp;       rf1 = *(const float4*)(rp + 4);
        rf2 = *(const float4*)(rp + 8); rf3 = *(const float4*)(rp + 12);
    };
    loadT(0);

    __syncthreads();   // q_s visible
    s16x8 aq0 = *(const s16x8*)&q_s[16 * mi + fr][fg * 8];        // persistent q frags
    s16x8 aq1 = *(const s16x8*)&q_s[16 * mi + fr][32 + fg * 8];

    f32x4 opv0 = {0,0,0,0}, opv1 = {0,0,0,0};

    for (int t0 = 0; t0 < t_end; t0 += 32) {
        __syncthreads();   // prev tile's MFMA reads done before overwrite
        {   // write staged regs -> LDS (bf16)
            s16x8 kp;
            kp[0]=f2bf(kf0.x); kp[1]=f2bf(kf0.y); kp[2]=f2bf(kf0.z); kp[3]=f2bf(kf0.w);
            kp[4]=f2bf(kf1.x); kp[5]=f2bf(kf1.y); kp[6]=f2bf(kf1.z); kp[7]=f2bf(kf1.w);
            *(s16x8*)&k_s[tk][ck] = kp;
            const int tsw = tk ^ (((ck >> 3) & 3) << 3);   // d>>3 == ck>>3 for j<8
            vT_s[ck + 0][tsw] = f2bf(vf0.x);
            vT_s[ck + 1][tsw] = f2bf(vf0.y);
            vT_s[ck + 2][tsw] = f2bf(vf0.z);
            vT_s[ck + 3][tsw] = f2bf(vf0.w);
            vT_s[ck + 4][tsw] = f2bf(vf1.x);
            vT_s[ck + 5][tsw] = f2bf(vf1.y);
            vT_s[ck + 6][tsw] = f2bf(vf1.z);
            vT_s[ck + 7][tsw] = f2bf(vf1.w);
            s16x8 r0, r1;
            r0[0]=f2bf(rf0.x); r0[1]=f2bf(rf0.y); r0[2]=f2bf(rf0.z); r0[3]=f2bf(rf0.w);
            r0[4]=f2bf(rf1.x); r0[5]=f2bf(rf1.y); r0[6]=f2bf(rf1.z); r0[7]=f2bf(rf1.w);
            r1[0]=f2bf(rf2.x); r1[1]=f2bf(rf2.y); r1[2]=f2bf(rf2.z); r1[3]=f2bf(rf2.w);
            r1[4]=f2bf(rf3.x); r1[5]=f2bf(rf3.y); r1[6]=f2bf(rf3.z); r1[7]=f2bf(rf3.w);
            *(s16x8*)&qr_s[iq][cq4]     = r0;
            *(s16x8*)&qr_s[iq][cq4 + 8] = r1;
        }
        if (t0 + 32 < t_end) loadT(t0 + 32);   // T14: issue early, hide under compute
        __syncthreads();

        {   // QK + QR MFMAs -> f32 score tiles
            s16x8 b0 = *(const s16x8*)&k_s[16 * nqk + fr][fg * 8];
            s16x8 b1 = *(const s16x8*)&k_s[16 * nqk + fr][32 + fg * 8];
            f32x4 ca = {0,0,0,0};
            ca = __builtin_amdgcn_mfma_f32_16x16x32_bf16(aq0, b0, ca, 0, 0, 0);
            ca = __builtin_amdgcn_mfma_f32_16x16x32_bf16(aq1, b1, ca, 0, 0, 0);
            #pragma unroll
            for (int rg = 0; rg < 4; ++rg)
                a_t[16 * mi + 4 * fg + rg][16 * nqk + fr] = ca[rg];
            #pragma unroll
            for (int i = 0; i < 2; ++i) {
                const int nf = nf0 + i;
                s16x8 c0 = *(const s16x8*)&qr_s[16 * nf + fr][fg * 8];
                s16x8 c1 = *(const s16x8*)&qr_s[16 * nf + fr][32 + fg * 8];
                f32x4 cb = {0,0,0,0};
                cb = __builtin_amdgcn_mfma_f32_16x16x32_bf16(aq0, c0, cb, 0, 0, 0);
                cb = __builtin_amdgcn_mfma_f32_16x16x32_bf16(aq1, c1, cb, 0, 0, 0);
                #pragma unroll
                for (int rg = 0; rg < 4; ++rg)
                    b_t[16 * mi + 4 * fg + rg][16 * nf + fr] = cb[rg];
            }
        }
        __syncthreads();

        {   // online softmax (f32), P -> bf16
            const int s_glob = q0 + sr;
            float sv[4];
            #pragma unroll
            for (int j = 0; j < 4; ++j) {
                const int c = sc0 + j;
                float scv = (a_t[sr][c] + b_t[sr][c + 31 - sr]) * 0.125f;
                sv[j] = (t0 + c > s_glob + MEM) ? -1e30f : scv;
            }
            float mx = fmaxf(fmaxf(sv[0], sv[1]), fmaxf(sv[2], sv[3]));
            mx = fmaxf(mx, __shfl_xor(mx, 1, 64));
            mx = fmaxf(mx, __shfl_xor(mx, 2, 64));
            mx = fmaxf(mx, __shfl_xor(mx, 4, 64));
            const float mo = row_m[sr];
            const float mn = fmaxf(mo, mx);
            const float scl = __expf(mo - mn);
            float sum = 0.0f;
            s16x4 pp;
            #pragma unroll
            for (int j = 0; j < 4; ++j) {
                float e = __expf(sv[j] - mn);
                sum += e;
                pp[j] = f2bf(e);
            }
            sum += __shfl_xor(sum, 1, 64);
            sum += __shfl_xor(sum, 2, 64);
            sum += __shfl_xor(sum, 4, 64);
            if ((tid & 7) == 0) {
                row_m[sr]  = mn;
                row_sc[sr] = scl;
                row_l[sr]  = row_l[sr] * scl + sum;
            }
            *(s16x4*)&p_s[sr][sc0] = pp;
        }
        __syncthreads();

        {   // PV: rescale acc, then acc += P @ V
            f32x4 scv;
            #pragma unroll
            for (int rg = 0; rg < 4; ++rg) scv[rg] = row_sc[16 * mi + 4 * fg + rg];
            #pragma unroll
            for (int rg = 0; rg < 4; ++rg) { opv0[rg] *= scv[rg]; opv1[rg] *= scv[rg]; }
            s16x8 ap = *(const s16x8*)&p_s[16 * mi + fr][fg * 8];
            const int d0 = 16 * nf0 + fr;
            const int d1 = d0 + 16;
            s16x8 bv0 = *(const s16x8*)&vT_s[d0][(fg ^ ((d0 >> 3) & 3)) * 8];
            s16x8 bv1 = *(const s16x8*)&vT_s[d1][(fg ^ ((d1 >> 3) & 3)) * 8];
            opv0 = __builtin_amdgcn_mfma_f32_16x16x32_bf16(ap, bv0, opv0, 0, 0, 0);
            opv1 = __builtin_amdgcn_mfma_f32_16x16x32_bf16(ap, bv1, opv1, 0, 0, 0);
        }
    }

    {   // epilogue: divide by denom, store f32
        #pragma unroll
        for (int rg = 0; rg < 4; ++rg) {
            const int row = 16 * mi + 4 * fg + rg;
            const float inv = 1.0f / row_l[row];
            float* op = ctx + ((size_t)(b * SS + q0 + row)) * DD + hoff;
            op[16 * nf0 + fr]      = opv0[rg] * inv;
            op[16 * nf0 + 16 + fr] = opv1[rg] * inv;
        }
    }
}

// ---------------- add + LayerNorm ----------------
__global__ __launch_bounds__(256) void addln_kernel(
    const float* __restrict__ a, const float* __restrict__ b,
    const float* __restrict__ g, const float* __restrict__ be,
    float* __restrict__ out)
{
    __shared__ float red[8];
    const int row = blockIdx.x;
    const int tid = threadIdx.x;
    const size_t base = (size_t)row * DD;
    const int c = tid * 4;
    float4 xa = *(const float4*)(a + base + c);
    float4 xb = *(const float4*)(b + base + c);
    float x0 = xa.x + xb.x, x1 = xa.y + xb.y, x2 = xa.z + xb.z, x3 = xa.w + xb.w;
    float s  = x0 + x1 + x2 + x3;
    float sq = x0 * x0 + x1 * x1 + x2 * x2 + x3 * x3;
    #pragma unroll
    for (int o = 32; o > 0; o >>= 1) {
        s  += __shfl_down(s, o, 64);
        sq += __shfl_down(sq, o, 64);
    }
    const int wv = tid >> 6;
    if ((tid & 63) == 0) { red[wv * 2] = s; red[wv * 2 + 1] = sq; }
    __syncthreads();
    float ts = red[0] + red[2] + red[4] + red[6];
    float tq = red[1] + red[3] + red[5] + red[7];
    float mu  = ts * (1.0f / DD);
    float var = tq * (1.0f / DD) - mu * mu;
    float rs  = rsqrtf(var + 1e-5f);
    float4 gv = *(const float4*)(g + c);
    float4 bv = *(const float4*)(be + c);
    float4 o4;
    o4.x = (x0 - mu) * rs * gv.x + bv.x;
    o4.y = (x1 - mu) * rs * gv.y + bv.y;
    o4.z = (x2 - mu) * rs * gv.z + bv.z;
    o4.w = (x3 - mu) * rs * gv.w + bv.w;
    *(float4*)(out + base + c) = o4;
}

// ---------------- embedding gather * sqrt(D) ----------------
__global__ __launch_bounds__(256) void embed_kernel(
    const int* __restrict__ inp, const float* __restrict__ emb, float* __restrict__ x)
{
    const int row = blockIdx.x;
    const int c = threadIdx.x * 4;
    const int idx = inp[row];
    float4 vv = *(const float4*)(emb + (size_t)idx * DD + c);
    vv.x *= 32.0f; vv.y *= 32.0f; vv.z *= 32.0f; vv.w *= 32.0f;
    *(float4*)(x + (size_t)row * DD + c) = vv;
}

// ---------------- concat mems[l] and x into x_tilde ----------------
__global__ __launch_bounds__(256) void concat_kernel(
    const float* __restrict__ mems_l, const float* __restrict__ x, float* __restrict__ xt)
{
    size_t i = ((size_t)blockIdx.x * 256 + threadIdx.x) * 4;
    size_t bt = i / DD;
    int d = (int)(i - bt * DD);
    int b = (int)(bt / TT);
    int t = (int)(bt - (size_t)b * TT);
    float4 vv;
    if (t < MEM) vv = *(const float4*)(mems_l + ((size_t)(b * MEM + t)) * DD + d);
    else         vv = *(const float4*)(x + ((size_t)(b * SS + (t - MEM))) * DD + d);
    *(float4*)(xt + i) = vv;
}

// ---------------- reversed sinusoidal position encoding ----------------
__global__ __launch_bounds__(256) void relenc_kernel(float* __restrict__ re)
{
    const int u = blockIdx.x;
    const int p = TT - 1 - u;
    const int i0 = threadIdx.x * 4;
    #pragma unroll
    for (int j = 0; j < 4; ++j) {
        int i = i0 + j;
        float ex   = (float)(2 * (i >> 1)) * (1.0f / DD);
        float invf = __expf(-ex * 9.210340371976184f);
        float ang  = (float)p * invf;
        re[(size_t)u * DD + i] = (i & 1) ? cosf(ang) : sinf(ang);
    }
}

extern "C" void kernel_launch(void* const* d_in, const int* in_sizes, int n_in,
                              void* d_out, int out_size, void* d_ws, size_t ws_size,
                              hipStream_t stream)
{
    const int*   inp  = (const int*)d_in[0];
    const float* mems = (const float*)d_in[1];
    const float* emb  = (const float*)d_in[2];
    const float* Wq   = (const float*)d_in[3];
    const float* bq   = (const float*)d_in[4];
    const float* Wke  = (const float*)d_in[5];
    const float* bke  = (const float*)d_in[6];
    const float* Wkr  = (const float*)d_in[7];
    const float* bkr  = (const float*)d_in[8];
    const float* Wv   = (const float*)d_in[9];
    const float* bv   = (const float*)d_in[10];
    const float* Wo   = (const float*)d_in[11];
    const float* bo   = (const float*)d_in[12];
    const float* ln1g = (const float*)d_in[13];
    const float* ln1b = (const float*)d_in[14];
    const float* W1   = (const float*)d_in[15];
    const float* b1   = (const float*)d_in[16];
    const float* W2   = (const float*)d_in[17];
    const float* b2   = (const float*)d_in[18];
    const float* ln2g = (const float*)d_in[19];
    const float* ln2b = (const float*)d_in[20];
    const float* Wh   = (const float*)d_in[21];
    const float* bh   = (const float*)d_in[22];
    const float* Wf   = (const float*)d_in[23];
    const float* bfb  = (const float*)d_in[24];

    float* ws = (float*)d_ws;
    size_t o = 0;
    float* rel  = ws + o; o += (size_t)TT * DD;
    float* x    = ws + o; o += (size_t)BB * SS * DD;
    float* xt   = ws + o; o += (size_t)BB * TT * DD;
    float* qb   = ws + o; o += (size_t)BB * SS * DD;
    float* kb   = ws + o; o += (size_t)BB * TT * DD;
    float* vb   = ws + o; o += (size_t)BB * TT * DD;
    float* Qrb  = ws + o; o += (size_t)TT * DD;
    float* ctxb = ws + o; o += (size_t)BB * SS * DD;
    float* ao   = ws + o; o += (size_t)BB * SS * DD;
    float* h1   = ws + o; o += (size_t)BB * SS * DD;
    float* ff1  = ws + o; o += (size_t)BB * SS * DD;
    float* ff2  = ws + o; o += (size_t)BB * SS * DD;

    relenc_kernel<<<TT, 256, 0, stream>>>(rel);
    embed_kernel<<<BB * SS, 256, 0, stream>>>(inp, emb, x);

    const dim3 gD(DD / GBN, (BB * SS) / GBM);
    const dim3 gT(DD / GBN, (BB * TT) / GBM);
    const dim3 gR(DD / GBN, TT / GBM);

    for (int l = 0; l < LL; ++l) {
        const size_t wo  = (size_t)l * DD * DD;
        const size_t bo_ = (size_t)l * DD;
        concat_kernel<<<(BB * TT * DD / 4) / 256, 256, 0, stream>>>(
            mems + (size_t)l * BB * MEM * DD, x, xt);
        gemm_kernel<<<gD, 256, 0, stream>>>(x,   Wq  + wo, bq  + bo_, qb,  DD, DD, 0);
        gemm_kernel<<<gT, 256, 0, stream>>>(xt,  Wke + wo, bke + bo_, kb,  DD, DD, 0);
        gemm_kernel<<<gT, 256, 0, stream>>>(xt,  Wv  + wo, bv  + bo_, vb,  DD, DD, 0);
        gemm_kernel<<<gR, 256, 0, stream>>>(rel, Wkr + wo, bkr + bo_, Qrb, DD, DD, 0);
        attn_kernel<<<dim3(SS / 32 * BB * NH), 256, 0, stream>>>(qb, kb, vb, Qrb, ctxb);
        gemm_kernel<<<gD, 256, 0, stream>>>(ctxb, Wo + wo, bo + bo_, ao, DD, DD, 0);
        addln_kernel<<<BB * SS, 256, 0, stream>>>(x, ao, ln1g + bo_, ln1b + bo_, h1);
        gemm_kernel<<<gD, 256, 0, stream>>>(h1,  W1 + wo, b1 + bo_, ff1, DD, DD, 1);
        gemm_kernel<<<gD, 256, 0, stream>>>(ff1, W2 + wo, b2 + bo_, ff2, DD, DD, 0);
        addln_kernel<<<BB * SS, 256, 0, stream>>>(h1, ff2, ln2g + bo_, ln2b + bo_, x);
    }

    gemm_kernel<<<gD, 256, 0, stream>>>(x, Wh, bh, qb, DD, DD, 1);
    gemm_kernel<<<dim3(VV / GBN, (BB * SS) / GBM), 256, 0, stream>>>(
        qb, Wf, bfb, (float*)d_out, VV, DD, 0);
}

// Round 4
// 1549.123 us; speedup vs baseline: 4.2576x; 1.3477x over previous
//
#include <hip/hip_runtime.h>
#include <hip/hip_bf16.h>
#include <math.h>

typedef __attribute__((ext_vector_type(4))) float f32x4;
typedef __attribute__((ext_vector_type(8))) short s16x8;
typedef __attribute__((ext_vector_type(4))) short s16x4;

#define BB 2
#define SS 1024
#define MEM 1024
#define DD 1024
#define LL 4
#define VV 32000
#define TT 2048
#define NH 16
#define DH 64

__device__ __forceinline__ short f2bf(float f) {
    unsigned u = __float_as_uint(f);
    u += 0x7fffu + ((u >> 16) & 1u);   // round-to-nearest-even
    return (short)(u >> 16);
}

__device__ __forceinline__ float gelu_f(float x) {
    return 0.5f * x * (1.0f + erff(x * 0.70710678118654752f));
}

__device__ __forceinline__ void gll16(const short* g, short* l) {
    __builtin_amdgcn_global_load_lds(
        (__attribute__((address_space(1))) void*)(short*)g,
        (__attribute__((address_space(3))) void*)l, 16, 0, 0);
}

// ---------------- GEMM: C(M,N) = act(A @ Wt^T + bias), all-bf16 inputs ----
// A [M][K] bf16 row-major; Bt [N][K] bf16 (pre-transposed weight).
// Tile BM=WM*32 x BN=WN*32, BK=64, 4 waves (2x2), wave tile WM*16 x WN*16 x2.
// LDS slot layout: slot s (16B) = [block16 = s>>7][kslice = (s>>4)&7][fr = s&15]
// -> every wave frag ds_read_b128 touches 64 distinct 16B slots (conflict-free).
template<int WM, int WN>
__global__ __launch_bounds__(256) void gemm_bf16(
    const short* __restrict__ A, const short* __restrict__ Bt,
    const float* __restrict__ bias, void* __restrict__ Cv,
    int N, int K, int act, int obf)
{
    constexpr int BM = WM * 32, BN = WN * 32;
    constexpr int NA = BM / 32, NB = BN / 32;   // 16B slots per thread
    __shared__ short a_s[BM * 64];
    __shared__ short b_s[BN * 64];
    const int tid  = threadIdx.x;
    const int lane = tid & 63;
    const int wave = tid >> 6;
    const int wr = wave >> 1, wc = wave & 1;
    const int fr = lane & 15, fg = lane >> 4;
    const size_t m0 = (size_t)blockIdx.y * BM;
    const size_t n0 = (size_t)blockIdx.x * BN;

    const short* gA[NA]; short* lA[NA];
    const short* gB[NB]; short* lB[NB];
    #pragma unroll
    for (int i = 0; i < NA; ++i) {
        const int s   = i * 256 + tid;
        const int row = (s >> 7) * 16 + (s & 15);
        const int kof = ((s >> 4) & 7) * 8;
        gA[i] = A + (m0 + row) * (size_t)K + kof;
        lA[i] = &a_s[s * 8];
    }
    #pragma unroll
    for (int i = 0; i < NB; ++i) {
        const int s   = i * 256 + tid;
        const int nn  = (s >> 7) * 16 + (s & 15);
        const int kof = ((s >> 4) & 7) * 8;
        gB[i] = Bt + (n0 + nn) * (size_t)K + kof;
        lB[i] = &b_s[s * 8];
    }

    f32x4 acc[WM][WN] = {};

    #pragma unroll
    for (int i = 0; i < NA; ++i) gll16(gA[i], lA[i]);
    #pragma unroll
    for (int i = 0; i < NB; ++i) gll16(gB[i], lB[i]);

    for (int k0 = 0; k0 < K; k0 += 64) {
        __syncthreads();   // vmcnt drained by compiler -> staged tile visible
        s16x8 af[WM][2], bf[WN][2];
        #pragma unroll
        for (int mi = 0; mi < WM; ++mi)
            #pragma unroll
            for (int h = 0; h < 2; ++h)
                af[mi][h] = *(const s16x8*)&a_s[((wr*WM + mi)*128 + (h*4 + fg)*16 + fr) * 8];
        #pragma unroll
        for (int ni = 0; ni < WN; ++ni)
            #pragma unroll
            for (int h = 0; h < 2; ++h)
                bf[ni][h] = *(const s16x8*)&b_s[((wc*WN + ni)*128 + (h*4 + fg)*16 + fr) * 8];
        if (k0 + 64 < K) {
            __syncthreads();   // all frag reads done -> safe to restage
            #pragma unroll
            for (int i = 0; i < NA; ++i) gll16(gA[i] + k0 + 64, lA[i]);
            #pragma unroll
            for (int i = 0; i < NB; ++i) gll16(gB[i] + k0 + 64, lB[i]);
        }
        #pragma unroll
        for (int mi = 0; mi < WM; ++mi)
            #pragma unroll
            for (int ni = 0; ni < WN; ++ni) {
                acc[mi][ni] = __builtin_amdgcn_mfma_f32_16x16x32_bf16(
                    af[mi][0], bf[ni][0], acc[mi][ni], 0, 0, 0);
                acc[mi][ni] = __builtin_amdgcn_mfma_f32_16x16x32_bf16(
                    af[mi][1], bf[ni][1], acc[mi][ni], 0, 0, 0);
            }
    }

    float* Cf = (float*)Cv;
    short* Cb = (short*)Cv;
    #pragma unroll
    for (int mi = 0; mi < WM; ++mi) {
        #pragma unroll
        for (int ni = 0; ni < WN; ++ni) {
            const size_t r0 = m0 + wr*WM*16 + mi*16 + fg*4;
            const size_t c  = n0 + wc*WN*16 + ni*16 + fr;
            const float bb = bias[c];
            #pragma unroll
            for (int rg = 0; rg < 4; ++rg) {
                float vv = acc[mi][ni][rg] + bb;
                if (act) vv = gelu_f(vv);
                if (obf) Cb[(r0 + rg)*(size_t)N + c] = f2bf(vv);
                else     Cf[(r0 + rg)*(size_t)N + c] = vv;
            }
        }
    }
}

// ---------------- weight transpose+convert: W[k][n] f32 -> Wt[n][k] bf16 ----
__global__ __launch_bounds__(256) void transpose7_kernel(
    const float* w0, const float* w1, const float* w2, const float* w3,
    const float* w4, const float* w5, const float* w6, short* out)
{
    __shared__ float t[32][33];
    const int z = blockIdx.z;
    const float* W;
    switch (z) {
        case 0: W = w0; break; case 1: W = w1; break; case 2: W = w2; break;
        case 3: W = w3; break; case 4: W = w4; break; case 5: W = w5; break;
        default: W = w6; break;
    }
    short* O = out + (size_t)z * DD * DD;
    const int tid = threadIdx.x;
    const int k0 = blockIdx.y * 32, n0 = blockIdx.x * 32;
    const int r = tid >> 3, c4 = (tid & 7) * 4;
    float4 v = *(const float4*)&W[(size_t)(k0 + r) * DD + n0 + c4];
    t[r][c4+0] = v.x; t[r][c4+1] = v.y; t[r][c4+2] = v.z; t[r][c4+3] = v.w;
    __syncthreads();
    short4 o;
    o.x = f2bf(t[c4+0][r]); o.y = f2bf(t[c4+1][r]);
    o.z = f2bf(t[c4+2][r]); o.w = f2bf(t[c4+3][r]);
    *(short4*)&O[(size_t)(n0 + r) * DD + k0 + c4] = o;
}

__global__ __launch_bounds__(256) void transposeF_kernel(
    const float* __restrict__ W, short* __restrict__ O)
{
    __shared__ float t[32][33];
    const int tid = threadIdx.x;
    const int k0 = blockIdx.y * 32, n0 = blockIdx.x * 32;
    const int r = tid >> 3, c4 = (tid & 7) * 4;
    float4 v = *(const float4*)&W[(size_t)(k0 + r) * VV + n0 + c4];
    t[r][c4+0] = v.x; t[r][c4+1] = v.y; t[r][c4+2] = v.z; t[r][c4+3] = v.w;
    __syncthreads();
    short4 o;
    o.x = f2bf(t[c4+0][r]); o.y = f2bf(t[c4+1][r]);
    o.z = f2bf(t[c4+2][r]); o.w = f2bf(t[c4+3][r]);
    *(short4*)&O[(size_t)(n0 + r) * DD + k0 + c4] = o;
}

// ---------------- MFMA flash attention, bf16 in/out ----------------
__global__ __launch_bounds__(256) void attn_kernel(
    const short* __restrict__ q, const short* __restrict__ k,
    const short* __restrict__ v, const short* __restrict__ Qr,
    short* __restrict__ ctx)
{
    __shared__ short q_s[32][72];
    __shared__ short k_s[32][72];
    __shared__ short qr_s[64][72];
    __shared__ short vT_s[64][40];   // [d][t^X], X = ((d>>3)&3)<<3
    __shared__ float a_t[32][37];
    __shared__ float b_t[32][68];
    __shared__ short p_s[32][40];
    __shared__ float row_m[32], row_l[32], row_sc[32];

    const int tid  = threadIdx.x;
    const int id   = blockIdx.x;
    const int bh   = id & 31;
    const int qi   = ((id >> 5) + bh) & 31;   // balance tile-count across CUs
    const int q0   = qi * 32;
    const int b    = bh >> 4;
    const int h    = bh & 15;
    const int hoff = h * DH;

    const int lane = tid & 63;
    const int wave = tid >> 6;
    const int fr   = lane & 15;
    const int fg   = lane >> 4;
    const int mi   = wave >> 1;
    const int nqk  = wave & 1;
    const int nf0  = (wave & 1) * 2;
    const int tk  = tid >> 3;
    const int ck  = (tid & 7) * 8;
    const int iq  = tid >> 2;
    const int cq4 = (tid & 3) * 16;
    const int sr  = tid >> 3;
    const int sc0 = (tid & 7) * 4;

    {   // stage q once (already bf16)
        const short* qp = q + ((size_t)(b * SS + q0 + tk)) * DD + hoff + ck;
        *(s16x8*)&q_s[tk][ck] = *(const s16x8*)qp;
    }
    if (tid < 32) { row_m[tid] = -INFINITY; row_l[tid] = 0.0f; }

    const int t_end  = q0 + 32 + MEM;
    const int u0base = SS - 1 - (q0 + 31);

    s16x8 kf, vf, rfA, rfB;
    auto loadT = [&](int t0) {
        kf = *(const s16x8*)(k + ((size_t)(b * TT + t0 + tk)) * DD + hoff + ck);
        vf = *(const s16x8*)(v + ((size_t)(b * TT + t0 + tk)) * DD + hoff + ck);
        int u = t0 + u0base + iq;
        u = u < 0 ? 0 : (u > TT - 1 ? TT - 1 : u);   // clamped rows are masked-only
        const short* rp = Qr + (size_t)u * DD + hoff + cq4;
        rfA = *(const s16x8*)rp;
        rfB = *(const s16x8*)(rp + 8);
    };
    loadT(0);

    __syncthreads();
    s16x8 aq0 = *(const s16x8*)&q_s[16 * mi + fr][fg * 8];
    s16x8 aq1 = *(const s16x8*)&q_s[16 * mi + fr][32 + fg * 8];

    f32x4 opv0 = {0,0,0,0}, opv1 = {0,0,0,0};

    for (int t0 = 0; t0 < t_end; t0 += 32) {
        __syncthreads();
        {   // staged regs -> LDS
            *(s16x8*)&k_s[tk][ck] = kf;
            const int tsw = tk ^ (((ck >> 3) & 3) << 3);
            vT_s[ck + 0][tsw] = vf[0];
            vT_s[ck + 1][tsw] = vf[1];
            vT_s[ck + 2][tsw] = vf[2];
            vT_s[ck + 3][tsw] = vf[3];
            vT_s[ck + 4][tsw] = vf[4];
            vT_s[ck + 5][tsw] = vf[5];
            vT_s[ck + 6][tsw] = vf[6];
            vT_s[ck + 7][tsw] = vf[7];
            *(s16x8*)&qr_s[iq][cq4]     = rfA;
            *(s16x8*)&qr_s[iq][cq4 + 8] = rfB;
        }
        if (t0 + 32 < t_end) loadT(t0 + 32);   // T14: issue early
        __syncthreads();

        {   // QK + QR MFMAs -> f32 score tiles
            s16x8 b0 = *(const s16x8*)&k_s[16 * nqk + fr][fg * 8];
            s16x8 b1 = *(const s16x8*)&k_s[16 * nqk + fr][32 + fg * 8];
            f32x4 ca = {0,0,0,0};
            ca = __builtin_amdgcn_mfma_f32_16x16x32_bf16(aq0, b0, ca, 0, 0, 0);
            ca = __builtin_amdgcn_mfma_f32_16x16x32_bf16(aq1, b1, ca, 0, 0, 0);
            #pragma unroll
            for (int rg = 0; rg < 4; ++rg)
                a_t[16 * mi + 4 * fg + rg][16 * nqk + fr] = ca[rg];
            #pragma unroll
            for (int i = 0; i < 2; ++i) {
                const int nf = nf0 + i;
                s16x8 c0 = *(const s16x8*)&qr_s[16 * nf + fr][fg * 8];
                s16x8 c1 = *(const s16x8*)&qr_s[16 * nf + fr][32 + fg * 8];
                f32x4 cb = {0,0,0,0};
                cb = __builtin_amdgcn_mfma_f32_16x16x32_bf16(aq0, c0, cb, 0, 0, 0);
                cb = __builtin_amdgcn_mfma_f32_16x16x32_bf16(aq1, c1, cb, 0, 0, 0);
                #pragma unroll
                for (int rg = 0; rg < 4; ++rg)
                    b_t[16 * mi + 4 * fg + rg][16 * nf + fr] = cb[rg];
            }
        }
        __syncthreads();

        {   // online softmax (f32), P -> bf16
            const int s_glob = q0 + sr;
            float sv[4];
            #pragma unroll
            for (int j = 0; j < 4; ++j) {
                const int c = sc0 + j;
                float scv = (a_t[sr][c] + b_t[sr][c + 31 - sr]) * 0.125f;
                sv[j] = (t0 + c > s_glob + MEM) ? -1e30f : scv;
            }
            float mx = fmaxf(fmaxf(sv[0], sv[1]), fmaxf(sv[2], sv[3]));
            mx = fmaxf(mx, __shfl_xor(mx, 1, 64));
            mx = fmaxf(mx, __shfl_xor(mx, 2, 64));
            mx = fmaxf(mx, __shfl_xor(mx, 4, 64));
            const float mo = row_m[sr];
            const float mn = fmaxf(mo, mx);
            const float scl = __expf(mo - mn);
            float sum = 0.0f;
            s16x4 pp;
            #pragma unroll
            for (int j = 0; j < 4; ++j) {
                float e = __expf(sv[j] - mn);
                sum += e;
                pp[j] = f2bf(e);
            }
            sum += __shfl_xor(sum, 1, 64);
            sum += __shfl_xor(sum, 2, 64);
            sum += __shfl_xor(sum, 4, 64);
            if ((tid & 7) == 0) {
                row_m[sr]  = mn;
                row_sc[sr] = scl;
                row_l[sr]  = row_l[sr] * scl + sum;
            }
            *(s16x4*)&p_s[sr][sc0] = pp;
        }
        __syncthreads();

        {   // PV: rescale acc, then acc += P @ V
            f32x4 scv;
            #pragma unroll
            for (int rg = 0; rg < 4; ++rg) scv[rg] = row_sc[16 * mi + 4 * fg + rg];
            #pragma unroll
            for (int rg = 0; rg < 4; ++rg) { opv0[rg] *= scv[rg]; opv1[rg] *= scv[rg]; }
            s16x8 ap = *(const s16x8*)&p_s[16 * mi + fr][fg * 8];
            const int d0 = 16 * nf0 + fr;
            const int d1 = d0 + 16;
            s16x8 bv0 = *(const s16x8*)&vT_s[d0][(fg ^ ((d0 >> 3) & 3)) * 8];
            s16x8 bv1 = *(const s16x8*)&vT_s[d1][(fg ^ ((d1 >> 3) & 3)) * 8];
            opv0 = __builtin_amdgcn_mfma_f32_16x16x32_bf16(ap, bv0, opv0, 0, 0, 0);
            opv1 = __builtin_amdgcn_mfma_f32_16x16x32_bf16(ap, bv1, opv1, 0, 0, 0);
        }
    }

    __syncthreads();
    {   // epilogue: divide by denom, store bf16
        #pragma unroll
        for (int rg = 0; rg < 4; ++rg) {
            const int row = 16 * mi + 4 * fg + rg;
            const float inv = 1.0f / row_l[row];
            short* op = ctx + ((size_t)(b * SS + q0 + row)) * DD + hoff;
            op[16 * nf0 + fr]      = f2bf(opv0[rg] * inv);
            op[16 * nf0 + 16 + fr] = f2bf(opv1[rg] * inv);
        }
    }
}

// ---------------- add + LayerNorm, dual f32 + bf16 output ----------------
__global__ __launch_bounds__(256) void addln_kernel(
    const float* __restrict__ a, const float* __restrict__ b,
    const float* __restrict__ g, const float* __restrict__ be,
    float* __restrict__ out32, short* __restrict__ outbf)
{
    __shared__ float red[8];
    const int row = blockIdx.x;
    const int tid = threadIdx.x;
    const size_t base = (size_t)row * DD;
    const int c = tid * 4;
    float4 xa = *(const float4*)(a + base + c);
    float4 xb = *(const float4*)(b + base + c);
    float x0 = xa.x + xb.x, x1 = xa.y + xb.y, x2 = xa.z + xb.z, x3 = xa.w + xb.w;
    float s  = x0 + x1 + x2 + x3;
    float sq = x0 * x0 + x1 * x1 + x2 * x2 + x3 * x3;
    #pragma unroll
    for (int o = 32; o > 0; o >>= 1) {
        s  += __shfl_down(s, o, 64);
        sq += __shfl_down(sq, o, 64);
    }
    const int wv = tid >> 6;
    if ((tid & 63) == 0) { red[wv * 2] = s; red[wv * 2 + 1] = sq; }
    __syncthreads();
    float ts = red[0] + red[2] + red[4] + red[6];
    float tq = red[1] + red[3] + red[5] + red[7];
    float mu  = ts * (1.0f / DD);
    float var = tq * (1.0f / DD) - mu * mu;
    float rs  = rsqrtf(var + 1e-5f);
    float4 gv = *(const float4*)(g + c);
    float4 bv = *(const float4*)(be + c);
    float4 o4;
    o4.x = (x0 - mu) * rs * gv.x + bv.x;
    o4.y = (x1 - mu) * rs * gv.y + bv.y;
    o4.z = (x2 - mu) * rs * gv.z + bv.z;
    o4.w = (x3 - mu) * rs * gv.w + bv.w;
    *(float4*)(out32 + base + c) = o4;
    short4 ob;
    ob.x = f2bf(o4.x); ob.y = f2bf(o4.y); ob.z = f2bf(o4.z); ob.w = f2bf(o4.w);
    *(short4*)(outbf + base + c) = ob;
}

// ---------------- embedding gather * sqrt(D), dual output ----------------
__global__ __launch_bounds__(256) void embed_kernel(
    const int* __restrict__ inp, const float* __restrict__ emb,
    float* __restrict__ x32, short* __restrict__ xbf)
{
    const int row = blockIdx.x;
    const int c = threadIdx.x * 4;
    const int idx = inp[row];
    float4 vv = *(const float4*)(emb + (size_t)idx * DD + c);
    vv.x *= 32.0f; vv.y *= 32.0f; vv.z *= 32.0f; vv.w *= 32.0f;
    *(float4*)(x32 + (size_t)row * DD + c) = vv;
    short4 ob;
    ob.x = f2bf(vv.x); ob.y = f2bf(vv.y); ob.z = f2bf(vv.z); ob.w = f2bf(vv.w);
    *(short4*)(xbf + (size_t)row * DD + c) = ob;
}

// ---------------- concat mems[l] (f32) and x (bf16) -> xt (bf16) ----------
__global__ __launch_bounds__(256) void concat_kernel(
    const float* __restrict__ mems_l, const short* __restrict__ xbf,
    short* __restrict__ xt)
{
    size_t i = ((size_t)blockIdx.x * 256 + threadIdx.x) * 8;
    size_t bt = i / DD;
    int d = (int)(i - bt * DD);
    int b = (int)(bt / TT);
    int t = (int)(bt - (size_t)b * TT);
    s16x8 o;
    if (t < MEM) {
        const float* mp = mems_l + ((size_t)(b * MEM + t)) * DD + d;
        float4 a0 = *(const float4*)mp;
        float4 a1 = *(const float4*)(mp + 4);
        o[0] = f2bf(a0.x); o[1] = f2bf(a0.y); o[2] = f2bf(a0.z); o[3] = f2bf(a0.w);
        o[4] = f2bf(a1.x); o[5] = f2bf(a1.y); o[6] = f2bf(a1.z); o[7] = f2bf(a1.w);
    } else {
        o = *(const s16x8*)(xbf + ((size_t)(b * SS + (t - MEM))) * DD + d);
    }
    *(s16x8*)(xt + i) = o;
}

// ---------------- reversed sinusoidal position encoding (bf16) ------------
__global__ __launch_bounds__(256) void relenc_kernel(short* __restrict__ re)
{
    const int u = blockIdx.x;
    const int p = TT - 1 - u;
    const int i0 = threadIdx.x * 4;
    short4 o;
    #pragma unroll
    for (int j = 0; j < 4; ++j) {
        int i = i0 + j;
        float ex   = (float)(2 * (i >> 1)) * (1.0f / DD);
        float invf = __expf(-ex * 9.210340371976184f);
        float ang  = (float)p * invf;
        float val  = (i & 1) ? cosf(ang) : sinf(ang);
        ((short*)&o)[j] = f2bf(val);
    }
    *(short4*)&re[(size_t)u * DD + i0] = o;
}

extern "C" void kernel_launch(void* const* d_in, const int* in_sizes, int n_in,
                              void* d_out, int out_size, void* d_ws, size_t ws_size,
                              hipStream_t stream)
{
    const int*   inp  = (const int*)d_in[0];
    const float* mems = (const float*)d_in[1];
    const float* emb  = (const float*)d_in[2];
    const float* Wq   = (const float*)d_in[3];
    const float* bq   = (const float*)d_in[4];
    const float* Wke  = (const float*)d_in[5];
    const float* bke  = (const float*)d_in[6];
    const float* Wkr  = (const float*)d_in[7];
    const float* bkr  = (const float*)d_in[8];
    const float* Wv   = (const float*)d_in[9];
    const float* bv   = (const float*)d_in[10];
    const float* Wo   = (const float*)d_in[11];
    const float* bo   = (const float*)d_in[12];
    const float* ln1g = (const float*)d_in[13];
    const float* ln1b = (const float*)d_in[14];
    const float* W1   = (const float*)d_in[15];
    const float* b1   = (const float*)d_in[16];
    const float* W2   = (const float*)d_in[17];
    const float* b2   = (const float*)d_in[18];
    const float* ln2g = (const float*)d_in[19];
    const float* ln2b = (const float*)d_in[20];
    const float* Wh   = (const float*)d_in[21];
    const float* bh   = (const float*)d_in[22];
    const float* Wf   = (const float*)d_in[23];
    const float* bfb  = (const float*)d_in[24];

    // ---- workspace layout (bytes). The first 64 MiB block is "transient":
    // it is dead by the time transposeF runs, so wft aliases it.
    char* wsb = (char*)d_ws;
    size_t off = 0;
    auto alloc = [&](size_t bytes) { char* p = wsb + off; off += (bytes + 255) & ~(size_t)255; return p; };
    float* h132  = (float*)alloc((size_t)BB*SS*DD*4);
    float* ao32  = (float*)alloc((size_t)BB*SS*DD*4);
    float* ff232 = (float*)alloc((size_t)BB*SS*DD*4);
    short* xt    = (short*)alloc((size_t)BB*TT*DD*2);
    short* qb    = (short*)alloc((size_t)BB*SS*DD*2);
    short* kb    = (short*)alloc((size_t)BB*TT*DD*2);
    short* vbuf  = (short*)alloc((size_t)BB*TT*DD*2);
    short* qr    = (short*)alloc((size_t)TT*DD*2);
    short* ctxb  = (short*)alloc((size_t)BB*SS*DD*2);
    short* ff1   = (short*)alloc((size_t)BB*SS*DD*2);
    // end of transient block (~64 MiB)
    float* x32   = (float*)alloc((size_t)BB*SS*DD*4);
    short* x_bf  = (short*)alloc((size_t)BB*SS*DD*2);
    short* whout = (short*)alloc((size_t)BB*SS*DD*2);
    short* rel   = (short*)alloc((size_t)TT*DD*2);
    short* wt7   = (short*)alloc((size_t)7*DD*DD*2);
    short* wft   = (short*)h132;   // aliases transient block (needs 62.5 MiB <= 64 MiB)

    relenc_kernel<<<TT, 256, 0, stream>>>(rel);
    embed_kernel<<<BB * SS, 256, 0, stream>>>(inp, emb, x32, x_bf);

    const dim3 gS(DD / 64, (BB * SS) / 64);    // (16,32) small-tile D x D
    const dim3 gTt(DD / 64, (BB * TT) / 64);   // (16,64) T-rows
    const dim3 gR(DD / 64, TT / 64);           // (16,32)
    const size_t WOFF = (size_t)DD * DD;

    for (int l = 0; l < LL; ++l) {
        const size_t wo  = (size_t)l * DD * DD;
        const size_t bo_ = (size_t)l * DD;
        transpose7_kernel<<<dim3(32, 32, 7), 256, 0, stream>>>(
            Wq + wo, Wke + wo, Wkr + wo, Wv + wo, Wo + wo, W1 + wo, W2 + wo, wt7);
        concat_kernel<<<(BB * TT * DD / 8) / 256, 256, 0, stream>>>(
            mems + (size_t)l * BB * MEM * DD, x_bf, xt);
        gemm_bf16<2,2><<<gS,  256, 0, stream>>>(x_bf, wt7 + 0*WOFF, bq  + bo_, qb,   DD, DD, 0, 1);
        gemm_bf16<2,2><<<gTt, 256, 0, stream>>>(xt,   wt7 + 1*WOFF, bke + bo_, kb,   DD, DD, 0, 1);
        gemm_bf16<2,2><<<gTt, 256, 0, stream>>>(xt,   wt7 + 3*WOFF, bv  + bo_, vbuf, DD, DD, 0, 1);
        gemm_bf16<2,2><<<gR,  256, 0, stream>>>(rel,  wt7 + 2*WOFF, bkr + bo_, qr,   DD, DD, 0, 1);
        attn_kernel<<<dim3((SS / 32) * BB * NH), 256, 0, stream>>>(qb, kb, vbuf, qr, ctxb);
        gemm_bf16<2,2><<<gS, 256, 0, stream>>>(ctxb, wt7 + 4*WOFF, bo + bo_, ao32, DD, DD, 0, 0);
        addln_kernel<<<BB * SS, 256, 0, stream>>>(x32, ao32, ln1g + bo_, ln1b + bo_, h132, (short*)x_bf);
        // NOTE: h1 bf16 mirror shares x_bf (x32 still holds x for this layer's
        // first residual, already consumed; x_bf is re-written by final addln)
        gemm_bf16<2,2><<<gS, 256, 0, stream>>>(x_bf, wt7 + 5*WOFF, b1 + bo_, ff1,   DD, DD, 1, 1);
        gemm_bf16<2,2><<<gS, 256, 0, stream>>>(ff1,  wt7 + 6*WOFF, b2 + bo_, ff232, DD, DD, 0, 0);
        addln_kernel<<<BB * SS, 256, 0, stream>>>(h132, ff232, ln2g + bo_, ln2b + bo_, x32, x_bf);
    }

    transpose7_kernel<<<dim3(32, 32, 1), 256, 0, stream>>>(
        Wh, Wh, Wh, Wh, Wh, Wh, Wh, wt7);
    transposeF_kernel<<<dim3(VV / 32, DD / 32), 256, 0, stream>>>(Wf, wft);
    gemm_bf16<2,2><<<gS, 256, 0, stream>>>(x_bf, wt7, bh, whout, DD, DD, 1, 1);
    gemm_bf16<4,4><<<dim3(VV / 128, (BB * SS) / 128), 256, 0, stream>>>(
        whout, wft, bfb, (float*)d_out, VV, DD, 0, 0);
}